// Round 1
// baseline (8796.372 us; speedup 1.0000x reference)
//
#include <hip/hip_runtime.h>

#define C_IN  512
#define C_OUT 512
#define HW    64
#define ICB   8
#define UB    4

// v[i] for i in 0..3 else 0, v = {1,3,3,1}
__device__ __forceinline__ float Gf(int i) {
    return (i < 0 || i > 3) ? 0.f : ((i == 1 || i == 2) ? 3.f : 1.f);
}

// out[n,oc,2uh+pu,2vh+pv] = sum_{t,s,ic} x[n,ic,uh+t-1,vh+s-1] * E6[2t+1-pu,2s+1-pv,ic,oc]
// E6[m,n,ic,oc] = (coef/16) * sum_{p,q} v[m-p] v[n-q] w[p,q,ic,oc]
__global__ __launch_bounds__(256) void conv_par_kernel(
        const float* __restrict__ x, const float* __restrict__ w,
        float* __restrict__ out) {
    const int octile = blockIdx.x;          // 0..7 : oc block of 64
    const int n      = blockIdx.y >> 4;     // 0..7
    const int uhb    = blockIdx.y & 15;     // 0..15 : uh block of 4
    const int pu     = blockIdx.z >> 1;
    const int pv     = blockIdx.z & 1;

    const int t    = threadIdx.x;
    const int lane = t & 63;    // vh
    const int wg   = t >> 6;    // oc sub-block of 16
    const int ocb  = octile * 64;
    const int uh0  = uhb * UB;

    __shared__ float xs[ICB][6][66];        // x tile with halo, 12.7 KB
    __shared__ float esw[9][ICB][64];       // w-chunk, then E-chunk (18.4 KB)

    float acc[UB][16];
    #pragma unroll
    for (int u = 0; u < UB; ++u)
        #pragma unroll
        for (int i = 0; i < 16; ++i) acc[u][i] = 0.f;

    // coef = 1 / (16 * sqrt(9*512))
    const float coef = 9.20711955e-04f;

    for (int icb = 0; icb < C_IN; icb += ICB) {
        __syncthreads();   // protect previous iteration's LDS reads

        // ---- stage x tile: rows uh0-1 .. uh0+4, cols -1..64, zero halo ----
        for (int e = t; e < ICB * 6 * 66; e += 256) {
            int col = e % 66;
            int tmp = e / 66;
            int row = tmp % 6;
            int ic  = tmp / 6;
            int h  = uh0 - 1 + row;
            int ww = col - 1;
            float v = 0.f;
            if (h >= 0 && h < HW && ww >= 0 && ww < HW)
                v = x[((n * C_IN + icb + ic) * HW + h) * HW + ww];
            xs[ic][row][col] = v;
        }
        // ---- stage w chunk [9][ICB][64] into esw ----
        for (int e = t; e < 9 * ICB * 64; e += 256) {
            int oc = e & 63;
            int ic = (e >> 6) & (ICB - 1);
            int pq = e >> 9;                 // p*3+q
            esw[pq][ic][oc] = w[(pq * C_IN + icb + ic) * C_OUT + ocb + oc];
        }
        __syncthreads();

        // ---- compute this parity's 9-tap E chunk (into registers first) ----
        float ereg[18];                      // 9*8*64 / 256 = 18 elems/thread
        #pragma unroll
        for (int j = 0; j < 18; ++j) {
            int e   = t + j * 256;
            int oc  = e & 63;
            int ic  = (e >> 6) & (ICB - 1);
            int tap = e >> 9;                // t3*3 + s3
            int t3  = tap / 3, s3 = tap - t3 * 3;
            int m   = 2 * t3 + 1 - pu;
            int nn  = 2 * s3 + 1 - pv;
            float gm0 = Gf(m),  gm1 = Gf(m - 1),  gm2 = Gf(m - 2);
            float gn0 = Gf(nn), gn1 = Gf(nn - 1), gn2 = Gf(nn - 2);
            float s =
              gm0 * (gn0 * esw[0][ic][oc] + gn1 * esw[1][ic][oc] + gn2 * esw[2][ic][oc])
            + gm1 * (gn0 * esw[3][ic][oc] + gn1 * esw[4][ic][oc] + gn2 * esw[5][ic][oc])
            + gm2 * (gn0 * esw[6][ic][oc] + gn1 * esw[7][ic][oc] + gn2 * esw[8][ic][oc]);
            ereg[j] = s * coef;
        }
        __syncthreads();
        #pragma unroll
        for (int j = 0; j < 18; ++j) {
            int e   = t + j * 256;
            int oc  = e & 63;
            int ic  = (e >> 6) & (ICB - 1);
            int tap = e >> 9;
            esw[tap][ic][oc] = ereg[j];
        }
        __syncthreads();

        // ---- main compute: 8 ic x 9 taps x (4 uh x 16 oc) FMA ----
        for (int ic = 0; ic < ICB; ++ic) {
            #pragma unroll
            for (int t3 = 0; t3 < 3; ++t3) {
                #pragma unroll
                for (int s3 = 0; s3 < 3; ++s3) {
                    const int tap = t3 * 3 + s3;
                    float ev[16];
                    #pragma unroll
                    for (int r = 0; r < 4; ++r)
                        *(float4*)&ev[r * 4] =
                            *(const float4*)&esw[tap][ic][wg * 16 + r * 4];
                    float xv[UB];
                    #pragma unroll
                    for (int u = 0; u < UB; ++u)
                        xv[u] = xs[ic][u + t3][lane + s3];
                    #pragma unroll
                    for (int u = 0; u < UB; ++u)
                        #pragma unroll
                        for (int i = 0; i < 16; ++i)
                            acc[u][i] += xv[u] * ev[i];
                }
            }
        }
    }

    // ---- epilogue: scatter to parity lattice ----
    #pragma unroll
    for (int u = 0; u < UB; ++u) {
        int urow = 2 * (uh0 + u) + pu;
        #pragma unroll
        for (int i = 0; i < 16; ++i) {
            int oc = ocb + wg * 16 + i;
            out[((n * C_OUT + oc) * 128 + urow) * 128 + 2 * lane + pv] = acc[u][i];
        }
    }
}

extern "C" void kernel_launch(void* const* d_in, const int* in_sizes, int n_in,
                              void* d_out, int out_size, void* d_ws, size_t ws_size,
                              hipStream_t stream) {
    const float* x = (const float*)d_in[0];   // (8,512,64,64) fp32
    const float* w = (const float*)d_in[1];   // (3,3,512,512) fp32 HWIO
    float* out = (float*)d_out;               // (8,512,128,128) fp32

    dim3 grid(8, 128, 4);   // (oc tiles, n*16+uhb, parity)
    conv_par_kernel<<<grid, 256, 0, stream>>>(x, w, out);
}

// Round 2
// 642.139 us; speedup vs baseline: 13.6985x; 13.6985x over previous
//
#include <hip/hip_runtime.h>
#include <stdint.h>

#define AS1 __attribute__((address_space(1)))
#define AS3 __attribute__((address_space(3)))

typedef short v8s __attribute__((ext_vector_type(8)));
typedef float v4f __attribute__((ext_vector_type(4)));

#define C_IN  512
#define C_OUT 512
#define HW    64
#define COEF  9.20711955e-04f   // 1 / (16 * sqrt(9*512))

// E_ws: [pu(2)][ocb(16)][icb(16)] chunks of 18*32*64 B = 36864 B (18432 shorts)
#define E_CHUNK_SHORTS 18432
#define E_WS_BYTES     (2u*16u*16u*36864u)            // 18,874,368
// x_tp: [n(8)][hp(66)][wp(66)][512 ic] bf16, zero-padded border
#define XT_SHORTS      ((size_t)8*66*66*512)          // 17,842,176
#define XT_BYTES       (XT_SHORTS*2)                  // 35,684,352
#define WS_NEED        ((size_t)E_WS_BYTES + XT_BYTES)

// LDS image: x tile [10 rows][18 cols][64B (4 swizzled 16B slots)] = 11520 B
//            E tile [18 taps][32 oc][64B]                          = 36864 B
#define LDS_X_BYTES 11520
#define LDS_E_OFF   11520
#define LDS_BYTES   48384

__device__ __forceinline__ float Gf(int i) {
    return (i < 0 || i > 3) ? 0.f : ((i == 1 || i == 2) ? 3.f : 1.f);
}
__device__ __forceinline__ short f2bf(float f) {
    uint32_t u = __float_as_uint(f);
    u += 0x7fffu + ((u >> 16) & 1u);
    return (short)(u >> 16);
}

// ---------------- precompute: x -> padded NHWC bf16, source-side XOR swizzle ----
// slot gs within each 64B icb-window holds logical ic-group (gs ^ ((wp>>1)&3))
__global__ __launch_bounds__(256) void xpose_kernel(const float* __restrict__ x,
                                                    short* __restrict__ xt) {
    int u = blockIdx.x * 256 + threadIdx.x;   // 8*66*66*64 = 2,230,272 units of 16B
    int g    = u & 63;
    int wq   = u >> 6;
    int wpos = wq % 66;
    int hq   = wq / 66;
    int hpos = hq % 66;
    int n    = hq / 66;

    v8s o = (v8s)0;
    if (hpos != 0 && hpos != 65 && wpos != 0 && wpos != 65) {
        int icb  = g >> 2;
        int gs   = g & 3;
        int glog = gs ^ ((wpos >> 1) & 3);
        int ic0  = icb * 32 + glog * 8;
        const float* src = x + ((size_t)(n * C_IN + ic0) * HW + (hpos - 1)) * HW + (wpos - 1);
        #pragma unroll
        for (int j = 0; j < 8; ++j)
            o[j] = f2bf(src[(size_t)j * HW * HW]);
    }
    *(v8s*)(xt + (size_t)u * 8) = o;
}

// ---------------- precompute: E in block-LDS image layout, bf16, swizzled -------
__global__ __launch_bounds__(256) void prep_e_kernel(const float* __restrict__ w,
                                                     short* __restrict__ ews) {
    int u = blockIdx.x * 256 + threadIdx.x;   // 1,179,648 units of 16B
    int g    = u & 3;
    int oc_l = (u >> 2) & 31;
    int tq   = u >> 7;
    int tap  = tq % 18;
    int rest = tq / 18;                        // pu*256 + ocb*16 + icb
    int icb  = rest & 15;
    int ocb  = (rest >> 4) & 15;
    int pu   = rest >> 8;
    int pv   = tap & 1;
    int ts   = tap >> 1;
    int t    = ts / 3, s = ts - t * 3;
    int m    = 2 * t + 1 - pu;
    int nn   = 2 * s + 1 - pv;
    int glog = g ^ ((oc_l >> 1) & 3);
    int ic0  = icb * 32 + glog * 8;
    int oc   = ocb * 32 + oc_l;

    v8s o;
    #pragma unroll
    for (int j = 0; j < 8; ++j) {
        float acc = 0.f;
        #pragma unroll
        for (int p = 0; p < 3; ++p) {
            float gm = Gf(m - p);
            if (gm != 0.f) {
                #pragma unroll
                for (int q = 0; q < 3; ++q) {
                    float gn = Gf(nn - q);
                    if (gn != 0.f)
                        acc += gm * gn * w[((size_t)(p * 3 + q) * C_IN + ic0 + j) * C_OUT + oc];
                }
            }
        }
        o[j] = f2bf(acc * COEF);
    }
    *(v8s*)(ews + (size_t)u * 8) = o;
}

// ---------------- main MFMA kernel ---------------------------------------------
__global__ __launch_bounds__(256) void conv_mfma_kernel(const short* __restrict__ xt,
                                                        const short* __restrict__ ews,
                                                        float* __restrict__ out) {
    int bid  = blockIdx.x;
    int wgid = (bid & 7) * 1024 + (bid >> 3);   // bijective XCD swizzle (8192 % 8 == 0)
    int vhb = wgid & 3;  wgid >>= 2;
    int uhb = wgid & 7;  wgid >>= 3;
    int n   = wgid & 7;  wgid >>= 3;
    int ocb = wgid & 15; wgid >>= 4;
    int pu  = wgid;
    const int uh0 = uhb * 8, vh0 = vhb * 16;

    __shared__ char lds_raw[LDS_BYTES];
    AS3 char* lds3 = (AS3 char*)lds_raw;

    const int tid  = threadIdx.x;
    const int lane = tid & 63;
    const int wid  = tid >> 6;
    const int wu   = wid >> 1;      // uh half
    const int wn   = wid & 1;       // oc half
    const int l15  = lane & 15;
    const int kg   = lane >> 4;

    // ---- hoisted staging addresses ----
    // E: per icb, copy 36864 B (9 wave-iters of 256 lanes x 16B)
    const short* esrc0 = ews + ((size_t)((pu * 16 + ocb) * 16)) * E_CHUNK_SHORTS + (size_t)tid * 8;
    // x: 720 16B-units; unit -> (row, col, slot)
    const short* gx[3];
    bool xact[3];
    #pragma unroll
    for (int it = 0; it < 3; ++it) {
        int unit  = it * 256 + tid;
        xact[it]  = unit < 720;
        int chunk = unit >> 2;
        int cslot = unit & 3;
        int row   = chunk / 18;
        int c     = chunk - row * 18;
        int ru = row, cu = c;
        if (!xact[it]) { ru = 0; cu = 0; }
        gx[it] = xt + ((size_t)((n * 66 + (uh0 + ru)) * 66) + (vh0 + cu)) * 512 + cslot * 8;
    }

    v4f acc[4][2];
    #pragma unroll
    for (int u = 0; u < 4; ++u)
        #pragma unroll
        for (int pv = 0; pv < 2; ++pv)
            acc[u][pv] = (v4f)0.f;

    const int oc_l = wn * 16 + l15;
    const int eswz = (kg ^ ((oc_l >> 1) & 3)) * 16;

    for (int icb = 0; icb < 16; ++icb) {
        __syncthreads();
        // stage E (linear global_load_lds copy, pre-swizzled in ws)
        const short* es = esrc0 + (size_t)icb * E_CHUNK_SHORTS;
        #pragma unroll
        for (int it = 0; it < 9; ++it) {
            __builtin_amdgcn_global_load_lds((const AS1 void*)(es + it * 2048),
                (AS3 void*)(lds3 + LDS_E_OFF + (it * 256 + wid * 64) * 16), 16, 0, 0);
        }
        // stage x (pre-swizzled source, linear dest)
        #pragma unroll
        for (int it = 0; it < 3; ++it) {
            if (xact[it])
                __builtin_amdgcn_global_load_lds((const AS1 void*)(gx[it] + icb * 32),
                    (AS3 void*)(lds3 + (it * 256 + wid * 64) * 16), 16, 0, 0);
        }
        __syncthreads();

        // compute: 3 s-shifts x (6 shared A rows) x 3 t x 2 pv x 4 uh
        #pragma unroll
        for (int s = 0; s < 3; ++s) {
            const int c   = l15 + s;
            const int xsw = (kg ^ ((c >> 1) & 3)) * 16;
            v8s A[6];
            #pragma unroll
            for (int rr = 0; rr < 6; ++rr) {
                int row = wu * 4 + rr;
                A[rr] = *(const v8s*)(lds_raw + (row * 18 + c) * 64 + xsw);
            }
            #pragma unroll
            for (int t = 0; t < 3; ++t) {
                #pragma unroll
                for (int pv = 0; pv < 2; ++pv) {
                    const int tap = (t * 3 + s) * 2 + pv;
                    v8s B = *(const v8s*)(lds_raw + LDS_E_OFF + tap * 2048 + oc_l * 64 + eswz);
                    #pragma unroll
                    for (int u = 0; u < 4; ++u)
                        acc[u][pv] = __builtin_amdgcn_mfma_f32_16x16x32_bf16(
                                         A[u + t], B, acc[u][pv], 0, 0, 0);
                }
            }
        }
    }

    // epilogue: D col = lane&15 (oc), row = (lane>>4)*4 + r (vh). Pack pv pairs -> float4.
    const int oc_g = ocb * 32 + oc_l;
    float* ob = out + ((size_t)(n * C_OUT + oc_g)) * 128 * 128;
    #pragma unroll
    for (int u = 0; u < 4; ++u) {
        int h = 2 * (uh0 + wu * 4 + u) + pu;
        #pragma unroll
        for (int rp = 0; rp < 2; ++rp) {
            int w0 = 2 * (vh0 + kg * 4 + rp * 2);
            v4f f;
            f[0] = acc[u][0][2 * rp];
            f[1] = acc[u][1][2 * rp];
            f[2] = acc[u][0][2 * rp + 1];
            f[3] = acc[u][1][2 * rp + 1];
            *(v4f*)(ob + (size_t)h * 128 + w0) = f;
        }
    }
}

// ---------------- fallback (validated round-1 VALU kernel) ----------------------
#define ICB 8
#define UB  4
__global__ __launch_bounds__(256) void conv_par_kernel(
        const float* __restrict__ x, const float* __restrict__ w,
        float* __restrict__ out) {
    const int octile = blockIdx.x;
    const int n      = blockIdx.y >> 4;
    const int uhb    = blockIdx.y & 15;
    const int pu     = blockIdx.z >> 1;
    const int pv     = blockIdx.z & 1;
    const int t    = threadIdx.x;
    const int lane = t & 63;
    const int wg   = t >> 6;
    const int ocb  = octile * 64;
    const int uh0  = uhb * UB;
    __shared__ float xs[ICB][6][66];
    __shared__ float esw[9][ICB][64];
    float acc[UB][16];
    #pragma unroll
    for (int u = 0; u < UB; ++u)
        #pragma unroll
        for (int i = 0; i < 16; ++i) acc[u][i] = 0.f;
    for (int icb = 0; icb < C_IN; icb += ICB) {
        __syncthreads();
        for (int e = t; e < ICB * 6 * 66; e += 256) {
            int col = e % 66; int tmp = e / 66; int row = tmp % 6; int ic = tmp / 6;
            int h = uh0 - 1 + row; int ww = col - 1;
            float v = 0.f;
            if (h >= 0 && h < HW && ww >= 0 && ww < HW)
                v = x[((n * C_IN + icb + ic) * HW + h) * HW + ww];
            xs[ic][row][col] = v;
        }
        for (int e = t; e < 9 * ICB * 64; e += 256) {
            int oc = e & 63; int ic = (e >> 6) & (ICB - 1); int pq = e >> 9;
            esw[pq][ic][oc] = w[(pq * C_IN + icb + ic) * C_OUT + ocb + oc];
        }
        __syncthreads();
        float ereg[18];
        #pragma unroll
        for (int j = 0; j < 18; ++j) {
            int e = t + j * 256; int oc = e & 63; int ic = (e >> 6) & (ICB - 1);
            int tap = e >> 9; int t3 = tap / 3, s3 = tap - t3 * 3;
            int m = 2 * t3 + 1 - pu; int nn = 2 * s3 + 1 - pv;
            float gm0 = Gf(m), gm1 = Gf(m - 1), gm2 = Gf(m - 2);
            float gn0 = Gf(nn), gn1 = Gf(nn - 1), gn2 = Gf(nn - 2);
            float s =
              gm0 * (gn0 * esw[0][ic][oc] + gn1 * esw[1][ic][oc] + gn2 * esw[2][ic][oc])
            + gm1 * (gn0 * esw[3][ic][oc] + gn1 * esw[4][ic][oc] + gn2 * esw[5][ic][oc])
            + gm2 * (gn0 * esw[6][ic][oc] + gn1 * esw[7][ic][oc] + gn2 * esw[8][ic][oc]);
            ereg[j] = s * COEF;
        }
        __syncthreads();
        #pragma unroll
        for (int j = 0; j < 18; ++j) {
            int e = t + j * 256; int oc = e & 63; int ic = (e >> 6) & (ICB - 1);
            int tap = e >> 9;
            esw[tap][ic][oc] = ereg[j];
        }
        __syncthreads();
        for (int ic = 0; ic < ICB; ++ic) {
            #pragma unroll
            for (int t3 = 0; t3 < 3; ++t3) {
                #pragma unroll
                for (int s3 = 0; s3 < 3; ++s3) {
                    const int tap = t3 * 3 + s3;
                    float ev[16];
                    #pragma unroll
                    for (int r = 0; r < 4; ++r)
                        *(float4*)&ev[r * 4] = *(const float4*)&esw[tap][ic][wg * 16 + r * 4];
                    float xv[UB];
                    #pragma unroll
                    for (int u = 0; u < UB; ++u) xv[u] = xs[ic][u + t3][lane + s3];
                    #pragma unroll
                    for (int u = 0; u < UB; ++u)
                        #pragma unroll
                        for (int i = 0; i < 16; ++i) acc[u][i] += xv[u] * ev[i];
                }
            }
        }
    }
    #pragma unroll
    for (int u = 0; u < UB; ++u) {
        int urow = 2 * (uh0 + u) + pu;
        #pragma unroll
        for (int i = 0; i < 16; ++i) {
            int oc = ocb + wg * 16 + i;
            out[((n * C_OUT + oc) * 128 + urow) * 128 + 2 * lane + pv] = acc[u][i];
        }
    }
}

extern "C" void kernel_launch(void* const* d_in, const int* in_sizes, int n_in,
                              void* d_out, int out_size, void* d_ws, size_t ws_size,
                              hipStream_t stream) {
    const float* x = (const float*)d_in[0];   // (8,512,64,64) fp32
    const float* w = (const float*)d_in[1];   // (3,3,512,512) fp32 HWIO
    float* out = (float*)d_out;               // (8,512,128,128) fp32

    if (ws_size >= WS_NEED) {
        short* ews = (short*)d_ws;
        short* xtp = (short*)((char*)d_ws + E_WS_BYTES);
        prep_e_kernel<<<1179648 / 256, 256, 0, stream>>>(w, ews);
        xpose_kernel<<<2230272 / 256, 256, 0, stream>>>(x, xtp);
        conv_mfma_kernel<<<8192, 256, 0, stream>>>(xtp, ews, out);
    } else {
        dim3 grid(8, 128, 4);
        conv_par_kernel<<<grid, 256, 0, stream>>>(x, w, out);
    }
}

// Round 3
// 591.151 us; speedup vs baseline: 14.8801x; 1.0863x over previous
//
#include <hip/hip_runtime.h>
#include <stdint.h>

#define AS1 __attribute__((address_space(1)))
#define AS3 __attribute__((address_space(3)))

typedef short v8s __attribute__((ext_vector_type(8)));
typedef float v4f __attribute__((ext_vector_type(4)));

#define C_IN  512
#define C_OUT 512
#define HW    64
#define COEF  9.20711955e-04f   // 1 / (16 * sqrt(9*512))

// E layout: [pu(2)][ocb(16)][wn(2)][icb(16)][tap(18)][lane(64)][8 bf16]
#define E_ICB_SHORTS (18*64*8)                 // 9216 shorts / icb slice
#define E_WS_BYTES   (2u*16u*2u*16u*18u*64u*16u)   // 18,874,368
// x_tp: [n(8)][hp(66)][wp(66)][512 ic] bf16, zero-padded border, ic-slot swizzled
#define XT_SHORTS    ((size_t)8*66*66*512)
#define XT_BYTES     (XT_SHORTS*2)             // 35,684,352
#define WS_NEED      ((size_t)E_WS_BYTES + XT_BYTES)

#define XTILE_BYTES 11520    // 10 rows * 18 cols * 64 B
#define LDS_BYTES   (2*XTILE_BYTES)

__device__ __forceinline__ float Gf(int i) {
    return (i < 0 || i > 3) ? 0.f : ((i == 1 || i == 2) ? 3.f : 1.f);
}
__device__ __forceinline__ short f2bf(float f) {
    uint32_t u = __float_as_uint(f);
    u += 0x7fffu + ((u >> 16) & 1u);
    return (short)(u >> 16);
}

// ---------------- precompute: x -> padded NHWC bf16 via LDS transpose ----------
// block: (n, hp, icb64). Coalesced float4 row reads; v8s coalesced writes.
__global__ __launch_bounds__(256) void xpose_kernel(const float* __restrict__ x,
                                                    short* __restrict__ xt) {
    const int b     = blockIdx.x;
    const int icb64 = b & 7;
    const int hp    = (b >> 3) % 66;
    const int n     = (b >> 3) / 66;
    const int t     = threadIdx.x;

    __shared__ short tile[64][80];   // [w][ic_local], stride 160 B (16B-aligned rows)

    const bool hvalid = (hp >= 1 && hp <= 64);
    if (hvalid) {
        #pragma unroll
        for (int r = 0; r < 4; ++r) {
            const int i  = (t >> 4) + r * 16;     // ic_local 0..63
            const int w0 = (t & 15) * 4;          // w 0..63
            const float* src = x + ((size_t)(n * C_IN + icb64 * 64 + i) * HW + (hp - 1)) * HW + w0;
            float4 v = *(const float4*)src;
            tile[w0 + 0][i] = f2bf(v.x);
            tile[w0 + 1][i] = f2bf(v.y);
            tile[w0 + 2][i] = f2bf(v.z);
            tile[w0 + 3][i] = f2bf(v.w);
        }
    }
    __syncthreads();

    // write 66 wp x 8 units of 16B (528 units); slot gs holds glog = gs ^ ((wp>>1)&3)
    for (int u = t; u < 528; u += 256) {
        const int wp = u >> 3;
        const int gs = u & 7;
        v8s o = (v8s)0;
        if (hvalid && wp >= 1 && wp <= 64) {
            const int glog = (gs & 3) ^ ((wp >> 1) & 3);
            const int il   = (gs >> 2) * 32 + glog * 8;
            o = *(const v8s*)&tile[wp - 1][il];
        }
        *(v8s*)(xt + ((size_t)(n * 66 + hp) * 66 + wp) * 512
                   + icb64 * 64 + (gs >> 2) * 32 + (gs & 3) * 8) = o;
    }
}

// ---------------- precompute: E in per-lane direct-load layout, bf16 -----------
__global__ __launch_bounds__(256) void prep_e_kernel(const float* __restrict__ w,
                                                     short* __restrict__ ews) {
    const int u    = blockIdx.x * 256 + threadIdx.x;   // 1,179,648 units of 16B
    const int lane = u & 63;
    const int tap  = (u >> 6) % 18;
    int rest       = (u >> 6) / 18;
    const int icb  = rest & 15; rest >>= 4;
    const int wn   = rest & 1;  rest >>= 1;
    const int ocb  = rest & 15; rest >>= 4;
    const int pu   = rest;
    const int pv   = tap & 1;
    const int ts   = tap >> 1;
    const int tt   = ts / 3, ss = ts - tt * 3;
    const int m    = 2 * tt + 1 - pu;
    const int nn   = 2 * ss + 1 - pv;
    const int ic0  = icb * 32 + (lane >> 4) * 8;
    const int oc   = ocb * 32 + wn * 16 + (lane & 15);

    v8s o;
    #pragma unroll
    for (int j = 0; j < 8; ++j) {
        float acc = 0.f;
        #pragma unroll
        for (int p = 0; p < 3; ++p) {
            float gm = Gf(m - p);
            if (gm != 0.f) {
                #pragma unroll
                for (int q = 0; q < 3; ++q) {
                    float gn = Gf(nn - q);
                    if (gn != 0.f)
                        acc += gm * gn * w[((size_t)(p * 3 + q) * C_IN + ic0 + j) * C_OUT + oc];
                }
            }
        }
        o[j] = f2bf(acc * COEF);
    }
    *(v8s*)(ews + (size_t)u * 8) = o;
}

// ---------------- main MFMA kernel ---------------------------------------------
__global__ __launch_bounds__(256, 3) void conv_mfma_kernel(const short* __restrict__ xt,
                                                           const short* __restrict__ ews,
                                                           float* __restrict__ out) {
    int bid  = blockIdx.x;
    int wgid = (bid & 7) * 1024 + (bid >> 3);   // bijective XCD swizzle (8192 % 8 == 0)
    int vhb = wgid & 3;  wgid >>= 2;
    int uhb = wgid & 7;  wgid >>= 3;
    int n   = wgid & 7;  wgid >>= 3;
    int ocb = wgid & 15; wgid >>= 4;
    int pu  = wgid;
    const int uh0 = uhb * 8, vh0 = vhb * 16;

    __shared__ char lds_raw[LDS_BYTES];
    AS3 char* lds3 = (AS3 char*)lds_raw;

    const int tid  = threadIdx.x;
    const int lane = tid & 63;
    const int wid  = tid >> 6;
    const int wu   = wid >> 1;      // uh half
    const int wn   = wid & 1;       // oc half
    const int l15  = lane & 15;
    const int kg   = lane >> 4;

    // x staging: 720 units of 16B -> (row, col, slot); pre-swizzled source
    const short* gx[3];
    bool xact[3];
    #pragma unroll
    for (int it = 0; it < 3; ++it) {
        int unit  = it * 256 + tid;
        xact[it]  = unit < 720;
        int chunk = unit >> 2;
        int cslot = unit & 3;
        int row   = chunk / 18;
        int c     = chunk - row * 18;
        if (!xact[it]) { row = 0; c = 0; }
        gx[it] = xt + ((size_t)(n * 66 + (uh0 + row)) * 66 + (vh0 + c)) * 512 + cslot * 8;
    }

    // E: per-lane direct global->reg, coalesced 1024B per wave-load
    const short* ebase = ews
        + ((size_t)((pu * 16 + ocb) * 2 + wn) * 16) * E_ICB_SHORTS
        + (size_t)lane * 8;

    v4f acc[4][2];
    #pragma unroll
    for (int u = 0; u < 4; ++u)
        #pragma unroll
        for (int pv = 0; pv < 2; ++pv)
            acc[u][pv] = (v4f)0.f;

#define STAGE(buf, icb_) do {                                                        \
    _Pragma("unroll")                                                                \
    for (int it = 0; it < 3; ++it) {                                                 \
        if (xact[it])                                                                \
            __builtin_amdgcn_global_load_lds((const AS1 void*)(gx[it] + (icb_) * 32),\
                (AS3 void*)(lds3 + (buf) * XTILE_BYTES + (it * 256 + wid * 64) * 16),\
                16, 0, 0);                                                           \
    }                                                                                \
} while (0)

    STAGE(0, 0);
    __syncthreads();

    for (int icb = 0; icb < 16; ++icb) {
        const int cur = icb & 1;
        if (icb < 15) STAGE(cur ^ 1, icb + 1);       // prefetch next tile (T3-minimum)
        const short* eic = ebase + (size_t)icb * E_ICB_SHORTS;
        const char*  xb  = lds_raw + cur * XTILE_BYTES;

        #pragma unroll
        for (int s = 0; s < 3; ++s) {
            const int c   = l15 + s;
            const int xsw = (kg ^ ((c >> 1) & 3)) * 16;
            v8s A[6];
            #pragma unroll
            for (int rr = 0; rr < 6; ++rr)
                A[rr] = *(const v8s*)(xb + ((wu * 4 + rr) * 18 + c) * 64 + xsw);
            v8s B[6];
            #pragma unroll
            for (int t = 0; t < 3; ++t)
                #pragma unroll
                for (int pv = 0; pv < 2; ++pv)
                    B[t * 2 + pv] = *(const v8s*)(eic + (size_t)((t * 3 + s) * 2 + pv) * 512);
            #pragma unroll
            for (int t = 0; t < 3; ++t)
                #pragma unroll
                for (int pv = 0; pv < 2; ++pv)
                    #pragma unroll
                    for (int u = 0; u < 4; ++u)
                        acc[u][pv] = __builtin_amdgcn_mfma_f32_16x16x32_bf16(
                                         A[u + t], B[t * 2 + pv], acc[u][pv], 0, 0, 0);
        }
        __syncthreads();    // drains the (old) prefetch loads; protects buf swap
    }
#undef STAGE

    // epilogue: D col = lane&15 (oc), row = (lane>>4)*4 + r (vh). Pack pv -> float4.
    const int oc_g = ocb * 32 + wn * 16 + l15;
    float* ob = out + ((size_t)(n * C_OUT + oc_g)) * 128 * 128;
    #pragma unroll
    for (int u = 0; u < 4; ++u) {
        int h = 2 * (uh0 + wu * 4 + u) + pu;
        #pragma unroll
        for (int rp = 0; rp < 2; ++rp) {
            int w0 = 2 * (vh0 + kg * 4 + rp * 2);
            v4f f;
            f[0] = acc[u][0][2 * rp];
            f[1] = acc[u][1][2 * rp];
            f[2] = acc[u][0][2 * rp + 1];
            f[3] = acc[u][1][2 * rp + 1];
            *(v4f*)(ob + (size_t)h * 128 + w0) = f;
        }
    }
}

// ---------------- fallback (validated round-1 VALU kernel) ----------------------
#define ICB 8
#define UB  4
__global__ __launch_bounds__(256) void conv_par_kernel(
        const float* __restrict__ x, const float* __restrict__ w,
        float* __restrict__ out) {
    const int octile = blockIdx.x;
    const int n      = blockIdx.y >> 4;
    const int uhb    = blockIdx.y & 15;
    const int pu     = blockIdx.z >> 1;
    const int pv     = blockIdx.z & 1;
    const int t    = threadIdx.x;
    const int lane = t & 63;
    const int wg   = t >> 6;
    const int ocb  = octile * 64;
    const int uh0  = uhb * UB;
    __shared__ float xs[ICB][6][66];
    __shared__ float esw[9][ICB][64];
    float acc[UB][16];
    #pragma unroll
    for (int u = 0; u < UB; ++u)
        #pragma unroll
        for (int i = 0; i < 16; ++i) acc[u][i] = 0.f;
    for (int icb = 0; icb < C_IN; icb += ICB) {
        __syncthreads();
        for (int e = t; e < ICB * 6 * 66; e += 256) {
            int col = e % 66; int tmp = e / 66; int row = tmp % 6; int ic = tmp / 6;
            int h = uh0 - 1 + row; int ww = col - 1;
            float v = 0.f;
            if (h >= 0 && h < HW && ww >= 0 && ww < HW)
                v = x[((n * C_IN + icb + ic) * HW + h) * HW + ww];
            xs[ic][row][col] = v;
        }
        for (int e = t; e < 9 * ICB * 64; e += 256) {
            int oc = e & 63; int ic = (e >> 6) & (ICB - 1); int pq = e >> 9;
            esw[pq][ic][oc] = w[(pq * C_IN + icb + ic) * C_OUT + ocb + oc];
        }
        __syncthreads();
        float ereg[18];
        #pragma unroll
        for (int j = 0; j < 18; ++j) {
            int e = t + j * 256; int oc = e & 63; int ic = (e >> 6) & (ICB - 1);
            int tap = e >> 9; int t3 = tap / 3, s3 = tap - t3 * 3;
            int m = 2 * t3 + 1 - pu; int nn = 2 * s3 + 1 - pv;
            float gm0 = Gf(m), gm1 = Gf(m - 1), gm2 = Gf(m - 2);
            float gn0 = Gf(nn), gn1 = Gf(nn - 1), gn2 = Gf(nn - 2);
            float s =
              gm0 * (gn0 * esw[0][ic][oc] + gn1 * esw[1][ic][oc] + gn2 * esw[2][ic][oc])
            + gm1 * (gn0 * esw[3][ic][oc] + gn1 * esw[4][ic][oc] + gn2 * esw[5][ic][oc])
            + gm2 * (gn0 * esw[6][ic][oc] + gn1 * esw[7][ic][oc] + gn2 * esw[8][ic][oc]);
            ereg[j] = s * COEF;
        }
        __syncthreads();
        #pragma unroll
        for (int j = 0; j < 18; ++j) {
            int e = t + j * 256; int oc = e & 63; int ic = (e >> 6) & (ICB - 1);
            int tap = e >> 9;
            esw[tap][ic][oc] = ereg[j];
        }
        __syncthreads();
        for (int ic = 0; ic < ICB; ++ic) {
            #pragma unroll
            for (int t3 = 0; t3 < 3; ++t3) {
                #pragma unroll
                for (int s3 = 0; s3 < 3; ++s3) {
                    const int tap = t3 * 3 + s3;
                    float ev[16];
                    #pragma unroll
                    for (int r = 0; r < 4; ++r)
                        *(float4*)&ev[r * 4] = *(const float4*)&esw[tap][ic][wg * 16 + r * 4];
                    float xv[UB];
                    #pragma unroll
                    for (int u = 0; u < UB; ++u) xv[u] = xs[ic][u + t3][lane + s3];
                    #pragma unroll
                    for (int u = 0; u < UB; ++u)
                        #pragma unroll
                        for (int i = 0; i < 16; ++i) acc[u][i] += xv[u] * ev[i];
                }
            }
        }
    }
    #pragma unroll
    for (int u = 0; u < UB; ++u) {
        int urow = 2 * (uh0 + u) + pu;
        #pragma unroll
        for (int i = 0; i < 16; ++i) {
            int oc = ocb + wg * 16 + i;
            out[((n * C_OUT + oc) * 128 + urow) * 128 + 2 * lane + pv] = acc[u][i];
        }
    }
}

extern "C" void kernel_launch(void* const* d_in, const int* in_sizes, int n_in,
                              void* d_out, int out_size, void* d_ws, size_t ws_size,
                              hipStream_t stream) {
    const float* x = (const float*)d_in[0];   // (8,512,64,64) fp32
    const float* w = (const float*)d_in[1];   // (3,3,512,512) fp32 HWIO
    float* out = (float*)d_out;               // (8,512,128,128) fp32

    if (ws_size >= WS_NEED) {
        short* ews = (short*)d_ws;
        short* xtp = (short*)((char*)d_ws + E_WS_BYTES);
        prep_e_kernel<<<4608, 256, 0, stream>>>(w, ews);
        xpose_kernel<<<4224, 256, 0, stream>>>(x, xtp);
        conv_mfma_kernel<<<8192, 256, 0, stream>>>(xtp, ews, out);
    } else {
        dim3 grid(8, 128, 4);
        conv_par_kernel<<<grid, 256, 0, stream>>>(x, w, out);
    }
}

// Round 4
// 544.568 us; speedup vs baseline: 16.1529x; 1.0855x over previous
//
#include <hip/hip_runtime.h>
#include <stdint.h>

#define AS1 __attribute__((address_space(1)))
#define AS3 __attribute__((address_space(3)))

typedef short v8s __attribute__((ext_vector_type(8)));
typedef float v4f __attribute__((ext_vector_type(4)));

#define C_IN  512
#define C_OUT 512
#define HW    64
#define COEF  9.20711955e-04f   // 1 / (16 * sqrt(9*512))

// E layout (R2 image): [pu(2)][ocb(16)][icb(16)] chunks of [tap(18)][oc_l(32)][slot(4)][16B]
#define E_CHUNK_SHORTS 18432
#define E_WS_BYTES     (2u*16u*16u*36864u)            // 18,874,368
// x_tp: [n(8)][hp(66)][wp(66)][512 ic] bf16, zero-padded border, ic-slot swizzled
#define XT_SHORTS      ((size_t)8*66*66*512)
#define XT_BYTES       (XT_SHORTS*2)                  // 35,684,352
#define WS_NEED        ((size_t)E_WS_BYTES + XT_BYTES)

// LDS: x tile [18 rows][18 cols][64B] = 20736 B, then E tile [18][32][64B] = 36864 B
#define XTILE_BYTES 20736
#define LDS_E_OFF   20736
#define LDS_BYTES   57600

__device__ __forceinline__ float Gf(int i) {
    return (i < 0 || i > 3) ? 0.f : ((i == 1 || i == 2) ? 3.f : 1.f);
}
__device__ __forceinline__ short f2bf(float f) {
    uint32_t u = __float_as_uint(f);
    u += 0x7fffu + ((u >> 16) & 1u);
    return (short)(u >> 16);
}

// ---------------- precompute: x -> padded NHWC bf16 via LDS transpose ----------
__global__ __launch_bounds__(256) void xpose_kernel(const float* __restrict__ x,
                                                    short* __restrict__ xt) {
    const int b     = blockIdx.x;
    const int icb64 = b & 7;
    const int hp    = (b >> 3) % 66;
    const int n     = (b >> 3) / 66;
    const int t     = threadIdx.x;

    __shared__ short tile[64][80];   // [w][ic_local]

    const bool hvalid = (hp >= 1 && hp <= 64);
    if (hvalid) {
        #pragma unroll
        for (int r = 0; r < 4; ++r) {
            const int i  = (t >> 4) + r * 16;     // ic_local 0..63
            const int w0 = (t & 15) * 4;          // w 0..63
            const float* src = x + ((size_t)(n * C_IN + icb64 * 64 + i) * HW + (hp - 1)) * HW + w0;
            float4 v = *(const float4*)src;
            tile[w0 + 0][i] = f2bf(v.x);
            tile[w0 + 1][i] = f2bf(v.y);
            tile[w0 + 2][i] = f2bf(v.z);
            tile[w0 + 3][i] = f2bf(v.w);
        }
    }
    __syncthreads();

    for (int u = t; u < 528; u += 256) {
        const int wp = u >> 3;
        const int gs = u & 7;
        v8s o = (v8s)0;
        if (hvalid && wp >= 1 && wp <= 64) {
            const int glog = (gs & 3) ^ ((wp >> 1) & 3);
            const int il   = (gs >> 2) * 32 + glog * 8;
            o = *(const v8s*)&tile[wp - 1][il];
        }
        *(v8s*)(xt + ((size_t)(n * 66 + hp) * 66 + wp) * 512
                   + icb64 * 64 + (gs >> 2) * 32 + (gs & 3) * 8) = o;
    }
}

// ---------------- precompute: E in block-LDS image layout, bf16, swizzled -------
__global__ __launch_bounds__(256) void prep_e_kernel(const float* __restrict__ w,
                                                     short* __restrict__ ews) {
    int u = blockIdx.x * 256 + threadIdx.x;   // 1,179,648 units of 16B
    int g    = u & 3;
    int oc_l = (u >> 2) & 31;
    int tq   = u >> 7;
    int tap  = tq % 18;
    int rest = tq / 18;                        // pu*256 + ocb*16 + icb
    int icb  = rest & 15;
    int ocb  = (rest >> 4) & 15;
    int pu   = rest >> 8;
    int pv   = tap & 1;
    int ts   = tap >> 1;
    int t    = ts / 3, s = ts - t * 3;
    int m    = 2 * t + 1 - pu;
    int nn   = 2 * s + 1 - pv;
    int glog = g ^ ((oc_l >> 1) & 3);
    int ic0  = icb * 32 + glog * 8;
    int oc   = ocb * 32 + oc_l;

    v8s o;
    #pragma unroll
    for (int j = 0; j < 8; ++j) {
        float acc = 0.f;
        #pragma unroll
        for (int p = 0; p < 3; ++p) {
            float gm = Gf(m - p);
            if (gm != 0.f) {
                #pragma unroll
                for (int q = 0; q < 3; ++q) {
                    float gn = Gf(nn - q);
                    if (gn != 0.f)
                        acc += gm * gn * w[((size_t)(p * 3 + q) * C_IN + ic0 + j) * C_OUT + oc];
                }
            }
        }
        o[j] = f2bf(acc * COEF);
    }
    *(v8s*)(ews + (size_t)u * 8) = o;
}

// ---------------- main MFMA kernel ---------------------------------------------
__global__ __launch_bounds__(256, 2) void conv_mfma_kernel(const short* __restrict__ xt,
                                                           const short* __restrict__ ews,
                                                           float* __restrict__ out) {
    int bid  = blockIdx.x;
    int wgid = (bid & 7) * 512 + (bid >> 3);   // bijective XCD swizzle (4096 % 8 == 0)
    int vhb = wgid & 3;  wgid >>= 2;
    int uhb = wgid & 3;  wgid >>= 2;
    int n   = wgid & 7;  wgid >>= 3;
    int ocb = wgid & 15; wgid >>= 4;
    int pu  = wgid;
    const int uh0 = uhb * 16, vh0 = vhb * 16;

    __shared__ char lds_raw[LDS_BYTES];
    AS3 char* lds3 = (AS3 char*)lds_raw;

    const int tid  = threadIdx.x;
    const int lane = tid & 63;
    const int wid  = tid >> 6;      // wave's uh-quarter (0..3)
    const int l15  = lane & 15;
    const int kg   = lane >> 4;

    // x staging: 1296 units of 16B -> (row 0..17, col 0..17, slot 0..3)
    const short* gx[6];
    bool xact[6];
    #pragma unroll
    for (int it = 0; it < 6; ++it) {
        int unit  = it * 256 + tid;
        xact[it]  = unit < 1296;
        int chunk = unit >> 2;
        int cslot = unit & 3;
        int row   = chunk / 18;
        int c     = chunk - row * 18;
        if (!xact[it]) { row = 0; c = 0; }
        gx[it] = xt + ((size_t)(n * 66 + (uh0 + row)) * 66 + (vh0 + c)) * 512 + cslot * 8;
    }
    // E staging source (36864 B per icb: 9 iters x 256 lanes x 16B)
    const short* esrc0 = ews + ((size_t)((pu * 16 + ocb) * 16)) * E_CHUNK_SHORTS + (size_t)tid * 8;

    v4f acc[4][2][2];   // [u][pv][wn]
    #pragma unroll
    for (int u = 0; u < 4; ++u)
        #pragma unroll
        for (int pv = 0; pv < 2; ++pv)
            #pragma unroll
            for (int wn = 0; wn < 2; ++wn)
                acc[u][pv][wn] = (v4f)0.f;

    const int eswz = (kg ^ ((l15 >> 1) & 3)) * 16;   // same for both wn (wn*16>>1 & 3 == 0)

    for (int icb = 0; icb < 16; ++icb) {
        __syncthreads();   // all waves done reading previous tiles
        // stage E (linear copy of pre-swizzled image)
        const short* es = esrc0 + (size_t)icb * E_CHUNK_SHORTS;
        #pragma unroll
        for (int it = 0; it < 9; ++it) {
            __builtin_amdgcn_global_load_lds((const AS1 void*)(es + it * 2048),
                (AS3 void*)(lds3 + LDS_E_OFF + (it * 256 + wid * 64) * 16), 16, 0, 0);
        }
        // stage x (pre-swizzled source, linear dest)
        #pragma unroll
        for (int it = 0; it < 6; ++it) {
            if (xact[it])
                __builtin_amdgcn_global_load_lds((const AS1 void*)(gx[it] + icb * 32),
                    (AS3 void*)(lds3 + (it * 256 + wid * 64) * 16), 16, 0, 0);
        }
        __syncthreads();   // compiler emits vmcnt(0) drain before this

        #pragma unroll
        for (int s = 0; s < 3; ++s) {
            const int c   = l15 + s;
            const int xsw = (kg ^ ((c >> 1) & 3)) * 16;
            v8s A[6];
            #pragma unroll
            for (int rr = 0; rr < 6; ++rr)
                A[rr] = *(const v8s*)(lds_raw + ((wid * 4 + rr) * 18 + c) * 64 + xsw);
            #pragma unroll
            for (int t = 0; t < 3; ++t) {
                #pragma unroll
                for (int pv = 0; pv < 2; ++pv) {
                    const int tap = (t * 3 + s) * 2 + pv;
                    #pragma unroll
                    for (int wn = 0; wn < 2; ++wn) {
                        v8s B = *(const v8s*)(lds_raw + LDS_E_OFF + tap * 2048
                                              + (wn * 16 + l15) * 64 + eswz);
                        #pragma unroll
                        for (int u = 0; u < 4; ++u)
                            acc[u][pv][wn] = __builtin_amdgcn_mfma_f32_16x16x32_bf16(
                                                 A[u + t], B, acc[u][pv][wn], 0, 0, 0);
                    }
                }
            }
        }
    }

    // epilogue: D col = lane&15 (oc), row = (lane>>4)*4 + r (vh). Pack pv -> float4.
    #pragma unroll
    for (int wn = 0; wn < 2; ++wn) {
        const int oc_g = ocb * 32 + wn * 16 + l15;
        float* ob = out + ((size_t)(n * C_OUT + oc_g)) * 128 * 128;
        #pragma unroll
        for (int u = 0; u < 4; ++u) {
            int h = 2 * (uh0 + wid * 4 + u) + pu;
            #pragma unroll
            for (int rp = 0; rp < 2; ++rp) {
                int w0 = 2 * (vh0 + kg * 4 + rp * 2);
                v4f f;
                f[0] = acc[u][0][wn][2 * rp];
                f[1] = acc[u][1][wn][2 * rp];
                f[2] = acc[u][0][wn][2 * rp + 1];
                f[3] = acc[u][1][wn][2 * rp + 1];
                *(v4f*)(ob + (size_t)h * 128 + w0) = f;
            }
        }
    }
}

// ---------------- fallback (validated round-1 VALU kernel) ----------------------
#define ICB 8
#define UB  4
__global__ __launch_bounds__(256) void conv_par_kernel(
        const float* __restrict__ x, const float* __restrict__ w,
        float* __restrict__ out) {
    const int octile = blockIdx.x;
    const int n      = blockIdx.y >> 4;
    const int uhb    = blockIdx.y & 15;
    const int pu     = blockIdx.z >> 1;
    const int pv     = blockIdx.z & 1;
    const int t    = threadIdx.x;
    const int lane = t & 63;
    const int wg   = t >> 6;
    const int ocb  = octile * 64;
    const int uh0  = uhb * UB;
    __shared__ float xs[ICB][6][66];
    __shared__ float esw[9][ICB][64];
    float acc[UB][16];
    #pragma unroll
    for (int u = 0; u < UB; ++u)
        #pragma unroll
        for (int i = 0; i < 16; ++i) acc[u][i] = 0.f;
    for (int icb = 0; icb < C_IN; icb += ICB) {
        __syncthreads();
        for (int e = t; e < ICB * 6 * 66; e += 256) {
            int col = e % 66; int tmp = e / 66; int row = tmp % 6; int ic = tmp / 6;
            int h = uh0 - 1 + row; int ww = col - 1;
            float v = 0.f;
            if (h >= 0 && h < HW && ww >= 0 && ww < HW)
                v = x[((n * C_IN + icb + ic) * HW + h) * HW + ww];
            xs[ic][row][col] = v;
        }
        for (int e = t; e < 9 * ICB * 64; e += 256) {
            int oc = e & 63; int ic = (e >> 6) & (ICB - 1); int pq = e >> 9;
            esw[pq][ic][oc] = w[(pq * C_IN + icb + ic) * C_OUT + ocb + oc];
        }
        __syncthreads();
        float ereg[18];
        #pragma unroll
        for (int j = 0; j < 18; ++j) {
            int e = t + j * 256; int oc = e & 63; int ic = (e >> 6) & (ICB - 1);
            int tap = e >> 9; int t3 = tap / 3, s3 = tap - t3 * 3;
            int m = 2 * t3 + 1 - pu; int nn = 2 * s3 + 1 - pv;
            float gm0 = Gf(m), gm1 = Gf(m - 1), gm2 = Gf(m - 2);
            float gn0 = Gf(nn), gn1 = Gf(nn - 1), gn2 = Gf(nn - 2);
            float s =
              gm0 * (gn0 * esw[0][ic][oc] + gn1 * esw[1][ic][oc] + gn2 * esw[2][ic][oc])
            + gm1 * (gn0 * esw[3][ic][oc] + gn1 * esw[4][ic][oc] + gn2 * esw[5][ic][oc])
            + gm2 * (gn0 * esw[6][ic][oc] + gn1 * esw[7][ic][oc] + gn2 * esw[8][ic][oc]);
            ereg[j] = s * COEF;
        }
        __syncthreads();
        #pragma unroll
        for (int j = 0; j < 18; ++j) {
            int e = t + j * 256; int oc = e & 63; int ic = (e >> 6) & (ICB - 1);
            int tap = e >> 9;
            esw[tap][ic][oc] = ereg[j];
        }
        __syncthreads();
        for (int ic = 0; ic < ICB; ++ic) {
            #pragma unroll
            for (int t3 = 0; t3 < 3; ++t3) {
                #pragma unroll
                for (int s3 = 0; s3 < 3; ++s3) {
                    const int tap = t3 * 3 + s3;
                    float ev[16];
                    #pragma unroll
                    for (int r = 0; r < 4; ++r)
                        *(float4*)&ev[r * 4] = *(const float4*)&esw[tap][ic][wg * 16 + r * 4];
                    float xv[UB];
                    #pragma unroll
                    for (int u = 0; u < UB; ++u) xv[u] = xs[ic][u + t3][lane + s3];
                    #pragma unroll
                    for (int u = 0; u < UB; ++u)
                        #pragma unroll
                        for (int i = 0; i < 16; ++i) acc[u][i] += xv[u] * ev[i];
                }
            }
        }
    }
    #pragma unroll
    for (int u = 0; u < UB; ++u) {
        int urow = 2 * (uh0 + u) + pu;
        #pragma unroll
        for (int i = 0; i < 16; ++i) {
            int oc = ocb + wg * 16 + i;
            out[((n * C_OUT + oc) * 128 + urow) * 128 + 2 * lane + pv] = acc[u][i];
        }
    }
}

extern "C" void kernel_launch(void* const* d_in, const int* in_sizes, int n_in,
                              void* d_out, int out_size, void* d_ws, size_t ws_size,
                              hipStream_t stream) {
    const float* x = (const float*)d_in[0];   // (8,512,64,64) fp32
    const float* w = (const float*)d_in[1];   // (3,3,512,512) fp32 HWIO
    float* out = (float*)d_out;               // (8,512,128,128) fp32

    if (ws_size >= WS_NEED) {
        short* ews = (short*)d_ws;
        short* xtp = (short*)((char*)d_ws + E_WS_BYTES);
        prep_e_kernel<<<4608, 256, 0, stream>>>(w, ews);
        xpose_kernel<<<4224, 256, 0, stream>>>(x, xtp);
        conv_mfma_kernel<<<4096, 256, 0, stream>>>(xtp, ews, out);
    } else {
        dim3 grid(8, 128, 4);
        conv_par_kernel<<<grid, 256, 0, stream>>>(x, w, out);
    }
}